// Round 1
// baseline (1352.083 us; speedup 1.0000x reference)
//
#include <hip/hip_runtime.h>
#include <hip/hip_bf16.h>

#define BB   2
#define SS   2048
#define DD   2048
#define HH   16
#define DHH  128
#define DFF  8192
#define MM   (BB*SS)   // 4096 tokens

typedef __hip_bfloat16 bf16;
typedef __bf16 bf16x8 __attribute__((ext_vector_type(8)));
typedef float  f32x4 __attribute__((ext_vector_type(4)));

// -------- async global->LDS, 16B per lane; lds base must be wave-uniform --------
__device__ __forceinline__ void gl2lds16(const void* g, void* lds_uniform_base) {
    __builtin_amdgcn_global_load_lds(
        (const __attribute__((address_space(1))) void*)g,
        (__attribute__((address_space(3))) void*)lds_uniform_base,
        16, 0, 0);
}

// ---------------------------------------------------------------------------
// LayerNorm: one block per row (D=2048), 256 threads, fp32 in -> bf16 out
// ---------------------------------------------------------------------------
__global__ __launch_bounds__(256) void ln_kernel(const float* __restrict__ x,
                                                 const float* __restrict__ g,
                                                 const float* __restrict__ b,
                                                 bf16* __restrict__ out) {
    int row = blockIdx.x, tid = threadIdx.x;
    const float4* xr = (const float4*)(x + (size_t)row * DD);
    float4 v0 = xr[tid];
    float4 v1 = xr[tid + 256];
    float s  = v0.x + v0.y + v0.z + v0.w + v1.x + v1.y + v1.z + v1.w;
    float s2 = v0.x*v0.x + v0.y*v0.y + v0.z*v0.z + v0.w*v0.w
             + v1.x*v1.x + v1.y*v1.y + v1.z*v1.z + v1.w*v1.w;
    #pragma unroll
    for (int m = 32; m >= 1; m >>= 1) { s += __shfl_xor(s, m); s2 += __shfl_xor(s2, m); }
    __shared__ float red[8];
    int wv = tid >> 6;
    if ((tid & 63) == 0) { red[wv] = s; red[wv + 4] = s2; }
    __syncthreads();
    s  = red[0] + red[1] + red[2] + red[3];
    s2 = red[4] + red[5] + red[6] + red[7];
    float mean = s * (1.0f / DD);
    float rs = rsqrtf(s2 * (1.0f / DD) - mean * mean + 1e-5f);
    bf16* o = out + (size_t)row * DD;
    int c0 = tid * 4, c1 = (tid + 256) * 4;
    float a0[4] = {v0.x, v0.y, v0.z, v0.w};
    float a1[4] = {v1.x, v1.y, v1.z, v1.w};
    #pragma unroll
    for (int j = 0; j < 4; j++) {
        o[c0 + j] = __float2bfloat16((a0[j] - mean) * rs * g[c0 + j] + b[c0 + j]);
        o[c1 + j] = __float2bfloat16((a1[j] - mean) * rs * g[c1 + j] + b[c1 + j]);
    }
}

// ---------------------------------------------------------------------------
// Transpose + fp32->bf16 cast: W[K][N] -> Wt[N][K]
// ---------------------------------------------------------------------------
__global__ __launch_bounds__(256) void transpose_cast(const float* __restrict__ W,
                                                      bf16* __restrict__ Wt,
                                                      int K, int N) {
    __shared__ float t[32][33];
    int n0 = blockIdx.x * 32, k0 = blockIdx.y * 32;
    int tx = threadIdx.x, ty = threadIdx.y;
    #pragma unroll
    for (int i = 0; i < 4; i++)
        t[ty + i * 8][tx] = W[(size_t)(k0 + ty + i * 8) * N + n0 + tx];
    __syncthreads();
    #pragma unroll
    for (int i = 0; i < 4; i++)
        Wt[(size_t)(n0 + ty + i * 8) * K + k0 + tx] = __float2bfloat16(t[tx][ty + i * 8]);
}

// ---------------------------------------------------------------------------
// V transpose per head: v[b*S+s][h*DH+dh] (bf16) -> vt[(b*H+h)*DH+dh][s]
// ---------------------------------------------------------------------------
__global__ __launch_bounds__(256) void transpose_v(const bf16* __restrict__ v,
                                                   bf16* __restrict__ vt) {
    __shared__ bf16 t[32][33];
    int s0 = blockIdx.x * 32, d0 = blockIdx.y * 32;
    int bh = blockIdx.z;
    int b = bh >> 4, h = bh & 15;
    int tx = threadIdx.x, ty = threadIdx.y;
    #pragma unroll
    for (int i = 0; i < 4; i++)
        t[ty + i * 8][tx] = v[(size_t)(b * SS + s0 + ty + i * 8) * DD + h * DHH + d0 + tx];
    __syncthreads();
    #pragma unroll
    for (int i = 0; i < 4; i++)
        vt[(size_t)((b * HH + h) * DHH + d0 + ty + i * 8) * SS + s0 + tx] = t[tx][ty + i * 8];
}

// ---------------------------------------------------------------------------
// GEMM: C[M][N] = A[M][K] @ Bt[N][K]^T + bias  (+ epilogue)
// epi 0: store bf16; epi 1: store fp32 (+resid); epi 2: gelu -> bf16
// BM=BN=128, BK=32, 256 threads (4 waves, 2x2), 4x4 MFMA 16x16x32 per wave
// ---------------------------------------------------------------------------
__global__ __launch_bounds__(256) void gemm_bt(const bf16* __restrict__ A,
                                               const bf16* __restrict__ Bt,
                                               const float* __restrict__ bias,
                                               const float* __restrict__ resid,
                                               void* __restrict__ Cout,
                                               int M, int N, int K, int epi) {
    __shared__ __align__(16) bf16 As[128 * 32];
    __shared__ __align__(16) bf16 Bs[128 * 32];
    int tid = threadIdx.x;
    int lane = tid & 63, wave = tid >> 6;
    int quad = lane >> 4, l15 = lane & 15;
    int wm = wave >> 1, wn = wave & 1;
    int bm0 = blockIdx.y * 128, bn0 = blockIdx.x * 128;
    const bf16* Ag = A + (size_t)bm0 * K;
    const bf16* Bg = Bt + (size_t)bn0 * K;
    f32x4 acc[4][4] = {};

    for (int kt = 0; kt < K; kt += 32) {
        __syncthreads();
        #pragma unroll
        for (int i = 0; i < 2; i++) {
            int chunk = i * 256 + tid;
            int row = chunk >> 2, c8 = chunk & 3;
            gl2lds16(Ag + (size_t)row * K + kt + c8 * 8, As + (i * 256 + wave * 64) * 8);
        }
        #pragma unroll
        for (int i = 0; i < 2; i++) {
            int chunk = i * 256 + tid;
            int row = chunk >> 2, c8 = chunk & 3;
            gl2lds16(Bg + (size_t)row * K + kt + c8 * 8, Bs + (i * 256 + wave * 64) * 8);
        }
        __syncthreads();
        bf16x8 af[4], bfr[4];
        #pragma unroll
        for (int mt = 0; mt < 4; mt++)
            af[mt] = *(const bf16x8*)(const void*)&As[(wm * 64 + mt * 16 + l15) * 32 + quad * 8];
        #pragma unroll
        for (int nt = 0; nt < 4; nt++)
            bfr[nt] = *(const bf16x8*)(const void*)&Bs[(wn * 64 + nt * 16 + l15) * 32 + quad * 8];
        #pragma unroll
        for (int mt = 0; mt < 4; mt++)
            #pragma unroll
            for (int nt = 0; nt < 4; nt++)
                acc[mt][nt] = __builtin_amdgcn_mfma_f32_16x16x32_bf16(af[mt], bfr[nt], acc[mt][nt], 0, 0, 0);
    }

    #pragma unroll
    for (int nt = 0; nt < 4; nt++) {
        int col = bn0 + wn * 64 + nt * 16 + l15;
        float bv = bias[col];
        #pragma unroll
        for (int mt = 0; mt < 4; mt++) {
            #pragma unroll
            for (int r = 0; r < 4; r++) {
                int row = bm0 + wm * 64 + mt * 16 + quad * 4 + r;
                size_t idx = (size_t)row * N + col;
                float v = acc[mt][nt][r] + bv;
                if (epi == 0) {
                    ((bf16*)Cout)[idx] = __float2bfloat16(v);
                } else if (epi == 1) {
                    ((float*)Cout)[idx] = v + resid[idx];
                } else {
                    float gv = 0.5f * v * (1.0f + erff(v * 0.70710678118654752f));
                    ((bf16*)Cout)[idx] = __float2bfloat16(gv);
                }
            }
        }
    }
}

// ---------------------------------------------------------------------------
// Flash attention: grid (S/64, H, B), 256 threads (4 waves).
// Q-tile 64 rows (16 per wave), K-tiles of 128 keys, online softmax.
// q,k: [token][D] bf16; vt: [(b*H+h)*DH+dh][s] bf16; out: [token][D] bf16
// ---------------------------------------------------------------------------
__global__ __launch_bounds__(256) void flash_attn(const bf16* __restrict__ qb,
                                                  const bf16* __restrict__ kb,
                                                  const bf16* __restrict__ vt,
                                                  bf16* __restrict__ out) {
    __shared__ __align__(16) bf16 Qs[64 * 128];
    __shared__ __align__(16) bf16 Ks[128 * 128];
    __shared__ __align__(16) bf16 Vs[128 * 128];   // [dh][key]
    __shared__ __align__(16) bf16 Ps[4 * 16 * 128];
    int tid = threadIdx.x;
    int lane = tid & 63, wave = tid >> 6;
    int quad = lane >> 4, l15 = lane & 15;
    int q0 = blockIdx.x * 64, h = blockIdx.y, b = blockIdx.z;
    int jlast = (q0 + 63) >> 7;
    const float scale = 0.088388347648318447f;  // 1/sqrt(128)

    #pragma unroll
    for (int i = 0; i < 4; i++) {
        int chunk = i * 256 + tid;
        int row = chunk >> 4, c8 = chunk & 15;
        gl2lds16(qb + (size_t)(b * SS + q0 + row) * DD + h * DHH + c8 * 8,
                 Qs + (i * 256 + wave * 64) * 8);
    }

    f32x4 oacc[8] = {};
    float mrun[4] = {-1e30f, -1e30f, -1e30f, -1e30f};
    float lrun[4] = {0.f, 0.f, 0.f, 0.f};

    for (int j = 0; j <= jlast; j++) {
        __syncthreads();
        #pragma unroll
        for (int i = 0; i < 8; i++) {
            int chunk = i * 256 + tid;
            int row = chunk >> 4, c8 = chunk & 15;
            gl2lds16(kb + (size_t)(b * SS + j * 128 + row) * DD + h * DHH + c8 * 8,
                     Ks + (i * 256 + wave * 64) * 8);
        }
        #pragma unroll
        for (int i = 0; i < 8; i++) {
            int chunk = i * 256 + tid;
            int row = chunk >> 4, c8 = chunk & 15;
            gl2lds16(vt + (size_t)((b * HH + h) * DHH + row) * SS + j * 128 + c8 * 8,
                     Vs + (i * 256 + wave * 64) * 8);
        }
        __syncthreads();

        // ---- S = Q K^T ----
        f32x4 sacc[8] = {};
        bf16x8 aq[4];
        #pragma unroll
        for (int kc = 0; kc < 4; kc++)
            aq[kc] = *(const bf16x8*)(const void*)&Qs[(wave * 16 + l15) * 128 + kc * 32 + quad * 8];
        #pragma unroll
        for (int n = 0; n < 8; n++)
            #pragma unroll
            for (int kc = 0; kc < 4; kc++) {
                bf16x8 bk = *(const bf16x8*)(const void*)&Ks[(n * 16 + l15) * 128 + kc * 32 + quad * 8];
                sacc[n] = __builtin_amdgcn_mfma_f32_16x16x32_bf16(aq[kc], bk, sacc[n], 0, 0, 0);
            }

        // ---- scale + causal mask + online softmax ----
        float mx[4] = {-1e30f, -1e30f, -1e30f, -1e30f};
        #pragma unroll
        for (int n = 0; n < 8; n++)
            #pragma unroll
            for (int r = 0; r < 4; r++) {
                float v = sacc[n][r] * scale;
                if (j == jlast) {
                    int key = j * 128 + n * 16 + l15;
                    int qr = q0 + wave * 16 + quad * 4 + r;
                    if (key > qr) v = -1e30f;
                }
                sacc[n][r] = v;
                mx[r] = fmaxf(mx[r], v);
            }
        #pragma unroll
        for (int r = 0; r < 4; r++) {
            mx[r] = fmaxf(mx[r], __shfl_xor(mx[r], 1));
            mx[r] = fmaxf(mx[r], __shfl_xor(mx[r], 2));
            mx[r] = fmaxf(mx[r], __shfl_xor(mx[r], 4));
            mx[r] = fmaxf(mx[r], __shfl_xor(mx[r], 8));
        }
        float alpha[4], rsum[4];
        #pragma unroll
        for (int r = 0; r < 4; r++) {
            float mn = fmaxf(mrun[r], mx[r]);
            alpha[r] = __expf(mrun[r] - mn);
            mrun[r] = mn;
            rsum[r] = 0.f;
        }
        #pragma unroll
        for (int n = 0; n < 8; n++)
            #pragma unroll
            for (int r = 0; r < 4; r++) {
                float p = __expf(sacc[n][r] - mrun[r]);
                sacc[n][r] = p;
                rsum[r] += p;
            }
        #pragma unroll
        for (int r = 0; r < 4; r++) {
            rsum[r] += __shfl_xor(rsum[r], 1);
            rsum[r] += __shfl_xor(rsum[r], 2);
            rsum[r] += __shfl_xor(rsum[r], 4);
            rsum[r] += __shfl_xor(rsum[r], 8);
            lrun[r] = lrun[r] * alpha[r] + rsum[r];
        }
        #pragma unroll
        for (int n = 0; n < 8; n++)
            #pragma unroll
            for (int r = 0; r < 4; r++)
                oacc[n][r] *= alpha[r];

        // ---- P (C-layout) -> LDS -> A-layout ----
        #pragma unroll
        for (int n = 0; n < 8; n++)
            #pragma unroll
            for (int r = 0; r < 4; r++)
                Ps[wave * 2048 + (quad * 4 + r) * 128 + n * 16 + l15] = __float2bfloat16(sacc[n][r]);
        __syncthreads();

        // ---- O += P @ V ----
        bf16x8 ap[4];
        #pragma unroll
        for (int kc = 0; kc < 4; kc++)
            ap[kc] = *(const bf16x8*)(const void*)&Ps[wave * 2048 + l15 * 128 + kc * 32 + quad * 8];
        #pragma unroll
        for (int n = 0; n < 8; n++)
            #pragma unroll
            for (int kc = 0; kc < 4; kc++) {
                bf16x8 bv = *(const bf16x8*)(const void*)&Vs[(n * 16 + l15) * 128 + kc * 32 + quad * 8];
                oacc[n] = __builtin_amdgcn_mfma_f32_16x16x32_bf16(ap[kc], bv, oacc[n], 0, 0, 0);
            }
    }

    #pragma unroll
    for (int n = 0; n < 8; n++)
        #pragma unroll
        for (int r = 0; r < 4; r++) {
            float v = oacc[n][r] / lrun[r];
            out[(size_t)(b * SS + q0 + wave * 16 + quad * 4 + r) * DD + h * DHH + n * 16 + l15] =
                __float2bfloat16(v);
        }
}

// ---------------------------------------------------------------------------
extern "C" void kernel_launch(void* const* d_in, const int* in_sizes, int n_in,
                              void* d_out, int out_size, void* d_ws, size_t ws_size,
                              hipStream_t stream) {
    (void)in_sizes; (void)n_in; (void)out_size; (void)ws_size;
    const float* x     = (const float*)d_in[0];
    const float* ln1_g = (const float*)d_in[2];
    const float* ln1_b = (const float*)d_in[3];
    const float* wq    = (const float*)d_in[4];
    const float* bq    = (const float*)d_in[5];
    const float* wk    = (const float*)d_in[6];
    const float* bk    = (const float*)d_in[7];
    const float* wv    = (const float*)d_in[8];
    const float* bv    = (const float*)d_in[9];
    const float* wo    = (const float*)d_in[10];
    const float* bo    = (const float*)d_in[11];
    const float* ln2_g = (const float*)d_in[12];
    const float* ln2_b = (const float*)d_in[13];
    const float* w_in  = (const float*)d_in[14];
    const float* b_in  = (const float*)d_in[15];
    const float* w_out = (const float*)d_in[16];
    const float* b_out = (const float*)d_in[17];
    float* out = (float*)d_out;

    char* ws = (char*)d_ws;
    const size_t MB = 1024 * 1024;
    bf16*  wt   = (bf16*)(ws + 0 * MB);     // 32 MB (reused per weight)
    bf16*  xn   = (bf16*)(ws + 32 * MB);    // 16 MB (later: attn out)
    bf16*  qb   = (bf16*)(ws + 48 * MB);    // 16 MB (later: xn2)
    float* x1   = (float*)(ws + 64 * MB);   // 32 MB
    bf16*  kbuf = (bf16*)(ws + 96 * MB);    // 16 MB
    bf16*  vbuf = (bf16*)(ws + 112 * MB);   // 16 MB
    bf16*  vtb  = (bf16*)(ws + 128 * MB);   // 16 MB
    bf16*  hb   = (bf16*)(ws + 96 * MB);    // 64 MB (96..160, overlaps k/v/vt after attn)
    bf16*  att  = xn;
    bf16*  xn2  = qb;

    dim3 t256(256), t32x8(32, 8);

    // LN1
    ln_kernel<<<MM, t256, 0, stream>>>(x, ln1_g, ln1_b, xn);

    // Q = xn @ wq + bq
    transpose_cast<<<dim3(DD / 32, DD / 32), t32x8, 0, stream>>>(wq, wt, DD, DD);
    gemm_bt<<<dim3(DD / 128, MM / 128), t256, 0, stream>>>(xn, wt, bq, nullptr, qb, MM, DD, DD, 0);
    // K
    transpose_cast<<<dim3(DD / 32, DD / 32), t32x8, 0, stream>>>(wk, wt, DD, DD);
    gemm_bt<<<dim3(DD / 128, MM / 128), t256, 0, stream>>>(xn, wt, bk, nullptr, kbuf, MM, DD, DD, 0);
    // V
    transpose_cast<<<dim3(DD / 32, DD / 32), t32x8, 0, stream>>>(wv, wt, DD, DD);
    gemm_bt<<<dim3(DD / 128, MM / 128), t256, 0, stream>>>(xn, wt, bv, nullptr, vbuf, MM, DD, DD, 0);
    // V transpose per head
    transpose_v<<<dim3(SS / 32, DHH / 32, BB * HH), t32x8, 0, stream>>>(vbuf, vtb);

    // attention -> att ([token][D] bf16)
    flash_attn<<<dim3(SS / 64, HH, BB), t256, 0, stream>>>(qb, kbuf, vtb, att);

    // x1 = x + att @ wo + bo
    transpose_cast<<<dim3(DD / 32, DD / 32), t32x8, 0, stream>>>(wo, wt, DD, DD);
    gemm_bt<<<dim3(DD / 128, MM / 128), t256, 0, stream>>>(att, wt, bo, x, x1, MM, DD, DD, 1);

    // LN2
    ln_kernel<<<MM, t256, 0, stream>>>(x1, ln2_g, ln2_b, xn2);

    // h = gelu(xn2 @ w_in + b_in)
    transpose_cast<<<dim3(DFF / 32, DD / 32), t32x8, 0, stream>>>(w_in, wt, DD, DFF);
    gemm_bt<<<dim3(DFF / 128, MM / 128), t256, 0, stream>>>(xn2, wt, b_in, nullptr, hb, MM, DFF, DD, 2);

    // out = x1 + h @ w_out + b_out
    transpose_cast<<<dim3(DD / 32, DFF / 32), t32x8, 0, stream>>>(w_out, wt, DFF, DD);
    gemm_bt<<<dim3(DD / 128, MM / 128), t256, 0, stream>>>(hb, wt, b_out, x1, out, MM, DD, DFF, 1);
}

// Round 2
// 1089.172 us; speedup vs baseline: 1.2414x; 1.2414x over previous
//
#include <hip/hip_runtime.h>
#include <hip/hip_bf16.h>

#define BB   2
#define SS   2048
#define DD   2048
#define HH   16
#define DHH  128
#define DFF  8192
#define MM   (BB*SS)   // 4096 tokens

typedef __hip_bfloat16 bf16;
typedef __bf16 bf16x8 __attribute__((ext_vector_type(8)));
typedef float  f32x4 __attribute__((ext_vector_type(4)));

// -------- async global->LDS, 16B per lane; lds base must be wave-uniform --------
__device__ __forceinline__ void gl2lds16(const void* g, void* lds_uniform_base) {
    __builtin_amdgcn_global_load_lds(
        (const __attribute__((address_space(1))) void*)g,
        (__attribute__((address_space(3))) void*)lds_uniform_base,
        16, 0, 0);
}

// ---------------------------------------------------------------------------
// LayerNorm: one block per row (D=2048), 256 threads, fp32 in -> bf16 out
// ---------------------------------------------------------------------------
__global__ __launch_bounds__(256) void ln_kernel(const float* __restrict__ x,
                                                 const float* __restrict__ g,
                                                 const float* __restrict__ b,
                                                 bf16* __restrict__ out) {
    int row = blockIdx.x, tid = threadIdx.x;
    const float4* xr = (const float4*)(x + (size_t)row * DD);
    float4 v0 = xr[tid];
    float4 v1 = xr[tid + 256];
    float s  = v0.x + v0.y + v0.z + v0.w + v1.x + v1.y + v1.z + v1.w;
    float s2 = v0.x*v0.x + v0.y*v0.y + v0.z*v0.z + v0.w*v0.w
             + v1.x*v1.x + v1.y*v1.y + v1.z*v1.z + v1.w*v1.w;
    #pragma unroll
    for (int m = 32; m >= 1; m >>= 1) { s += __shfl_xor(s, m); s2 += __shfl_xor(s2, m); }
    __shared__ float red[8];
    int wv = tid >> 6;
    if ((tid & 63) == 0) { red[wv] = s; red[wv + 4] = s2; }
    __syncthreads();
    s  = red[0] + red[1] + red[2] + red[3];
    s2 = red[4] + red[5] + red[6] + red[7];
    float mean = s * (1.0f / DD);
    float rs = rsqrtf(s2 * (1.0f / DD) - mean * mean + 1e-5f);
    bf16* o = out + (size_t)row * DD;
    int c0 = tid * 4, c1 = (tid + 256) * 4;
    float a0[4] = {v0.x, v0.y, v0.z, v0.w};
    float a1[4] = {v1.x, v1.y, v1.z, v1.w};
    #pragma unroll
    for (int j = 0; j < 4; j++) {
        o[c0 + j] = __float2bfloat16((a0[j] - mean) * rs * g[c0 + j] + b[c0 + j]);
        o[c1 + j] = __float2bfloat16((a1[j] - mean) * rs * g[c1 + j] + b[c1 + j]);
    }
}

// ---------------------------------------------------------------------------
// Transpose + fp32->bf16 cast: W[K][N] -> Wt[N][K]
// ---------------------------------------------------------------------------
__global__ __launch_bounds__(256) void transpose_cast(const float* __restrict__ W,
                                                      bf16* __restrict__ Wt,
                                                      int K, int N) {
    __shared__ float t[32][33];
    int n0 = blockIdx.x * 32, k0 = blockIdx.y * 32;
    int tx = threadIdx.x, ty = threadIdx.y;
    #pragma unroll
    for (int i = 0; i < 4; i++)
        t[ty + i * 8][tx] = W[(size_t)(k0 + ty + i * 8) * N + n0 + tx];
    __syncthreads();
    #pragma unroll
    for (int i = 0; i < 4; i++)
        Wt[(size_t)(n0 + ty + i * 8) * K + k0 + tx] = __float2bfloat16(t[tx][ty + i * 8]);
}

// ---------------------------------------------------------------------------
// V transpose per head: v[b*S+s][h*DH+dh] (bf16) -> vt[(b*H+h)*DH+dh][s]
// ---------------------------------------------------------------------------
__global__ __launch_bounds__(256) void transpose_v(const bf16* __restrict__ v,
                                                   bf16* __restrict__ vt) {
    __shared__ bf16 t[32][33];
    int s0 = blockIdx.x * 32, d0 = blockIdx.y * 32;
    int bh = blockIdx.z;
    int b = bh >> 4, h = bh & 15;
    int tx = threadIdx.x, ty = threadIdx.y;
    #pragma unroll
    for (int i = 0; i < 4; i++)
        t[ty + i * 8][tx] = v[(size_t)(b * SS + s0 + ty + i * 8) * DD + h * DHH + d0 + tx];
    __syncthreads();
    #pragma unroll
    for (int i = 0; i < 4; i++)
        vt[(size_t)((b * HH + h) * DHH + d0 + ty + i * 8) * SS + s0 + tx] = t[tx][ty + i * 8];
}

// ---------------------------------------------------------------------------
// GEMM: C[M][N] = A[M][K] @ Bt[N][K]^T + bias  (+ epilogue)
// epi 0: store bf16; epi 1: store fp32 (+resid); epi 2: gelu -> bf16
// BM=BN=128, BK=32, 256 threads (4 waves, 2x2), 4x4 MFMA 16x16x32 per wave
// ---------------------------------------------------------------------------
__global__ __launch_bounds__(256) void gemm_bt(const bf16* __restrict__ A,
                                               const bf16* __restrict__ Bt,
                                               const float* __restrict__ bias,
                                               const float* __restrict__ resid,
                                               void* __restrict__ Cout,
                                               int M, int N, int K, int epi) {
    __shared__ __align__(16) bf16 As[128 * 32];
    __shared__ __align__(16) bf16 Bs[128 * 32];
    int tid = threadIdx.x;
    int lane = tid & 63, wave = tid >> 6;
    int quad = lane >> 4, l15 = lane & 15;
    int wm = wave >> 1, wn = wave & 1;
    int bm0 = blockIdx.y * 128, bn0 = blockIdx.x * 128;
    const bf16* Ag = A + (size_t)bm0 * K;
    const bf16* Bg = Bt + (size_t)bn0 * K;
    f32x4 acc[4][4] = {};

    for (int kt = 0; kt < K; kt += 32) {
        __syncthreads();
        #pragma unroll
        for (int i = 0; i < 2; i++) {
            int chunk = i * 256 + tid;
            int row = chunk >> 2, c8 = chunk & 3;
            gl2lds16(Ag + (size_t)row * K + kt + c8 * 8, As + (i * 256 + wave * 64) * 8);
        }
        #pragma unroll
        for (int i = 0; i < 2; i++) {
            int chunk = i * 256 + tid;
            int row = chunk >> 2, c8 = chunk & 3;
            gl2lds16(Bg + (size_t)row * K + kt + c8 * 8, Bs + (i * 256 + wave * 64) * 8);
        }
        __syncthreads();
        bf16x8 af[4], bfr[4];
        #pragma unroll
        for (int mt = 0; mt < 4; mt++)
            af[mt] = *(const bf16x8*)(const void*)&As[(wm * 64 + mt * 16 + l15) * 32 + quad * 8];
        #pragma unroll
        for (int nt = 0; nt < 4; nt++)
            bfr[nt] = *(const bf16x8*)(const void*)&Bs[(wn * 64 + nt * 16 + l15) * 32 + quad * 8];
        #pragma unroll
        for (int mt = 0; mt < 4; mt++)
            #pragma unroll
            for (int nt = 0; nt < 4; nt++)
                acc[mt][nt] = __builtin_amdgcn_mfma_f32_16x16x32_bf16(af[mt], bfr[nt], acc[mt][nt], 0, 0, 0);
    }

    #pragma unroll
    for (int nt = 0; nt < 4; nt++) {
        int col = bn0 + wn * 64 + nt * 16 + l15;
        float bv = bias[col];
        #pragma unroll
        for (int mt = 0; mt < 4; mt++) {
            #pragma unroll
            for (int r = 0; r < 4; r++) {
                int row = bm0 + wm * 64 + mt * 16 + quad * 4 + r;
                size_t idx = (size_t)row * N + col;
                float v = acc[mt][nt][r] + bv;
                if (epi == 0) {
                    ((bf16*)Cout)[idx] = __float2bfloat16(v);
                } else if (epi == 1) {
                    ((float*)Cout)[idx] = v + resid[idx];
                } else {
                    float gv = 0.5f * v * (1.0f + erff(v * 0.70710678118654752f));
                    ((bf16*)Cout)[idx] = __float2bfloat16(gv);
                }
            }
        }
    }
}

// ---------------------------------------------------------------------------
// Flash attention v2: grid (S/128, H, B), 512 threads (8 waves).
// BM=128 Q rows (16 per wave), K-tiles of 128 keys, online softmax.
// All LDS tiles XOR-swizzled at 16B-group granularity: logical group g of
// row r is stored at physical group g^(r&15). Staging picks the global
// source per lane so the HW's fixed (base+lane*16) dest lands swizzled;
// fragment reads then hit banks 4*((c8^l15)%8) -> 2-way (free).
// q,k: [token][D] bf16; vt: [(b*H+h)*DH+dh][s] bf16; out: [token][D] bf16
// ---------------------------------------------------------------------------
__global__ __launch_bounds__(512) void flash_attn(const bf16* __restrict__ qb,
                                                  const bf16* __restrict__ kb,
                                                  const bf16* __restrict__ vt,
                                                  bf16* __restrict__ out) {
    __shared__ __align__(16) bf16 Qs[128 * 128];
    __shared__ __align__(16) bf16 Ks[128 * 128];
    __shared__ __align__(16) bf16 Vs[128 * 128];   // [dh][key]
    __shared__ __align__(16) bf16 Ps[8 * 16 * 128];
    int tid = threadIdx.x;
    int lane = tid & 63, wave = tid >> 6;
    int quad = lane >> 4, l15 = lane & 15;
    // causal load-balance: pair tile k with tile 15-k in adjacent dispatch ids
    int xr = blockIdx.x;
    int t = (xr & 1) ? (15 - (xr >> 1)) : (xr >> 1);
    int q0 = t * 128;
    int h = blockIdx.y, b = blockIdx.z;
    int jlast = t;
    const float scale = 0.088388347648318447f;  // 1/sqrt(128)

    int srow = tid >> 4;                    // 0..31 (row within 32-row chunk)
    int sgrp = (tid & 15) ^ (srow & 15);    // swizzled source 16B-group

    // ---- stage Q (swizzled) ----
    #pragma unroll
    for (int i = 0; i < 4; i++) {
        int row = i * 32 + srow;
        gl2lds16(qb + (size_t)(b * SS + q0 + row) * DD + h * DHH + sgrp * 8,
                 Qs + i * 4096 + wave * 512);
    }

    f32x4 oacc[8] = {};
    float mrun[4] = {-1e30f, -1e30f, -1e30f, -1e30f};
    float lrun[4] = {0.f, 0.f, 0.f, 0.f};

    for (int j = 0; j <= jlast; j++) {
        __syncthreads();
        #pragma unroll
        for (int i = 0; i < 4; i++) {
            int row = i * 32 + srow;
            gl2lds16(kb + (size_t)(b * SS + j * 128 + row) * DD + h * DHH + sgrp * 8,
                     Ks + i * 4096 + wave * 512);
        }
        #pragma unroll
        for (int i = 0; i < 4; i++) {
            int row = i * 32 + srow;
            gl2lds16(vt + (size_t)((b * HH + h) * DHH + row) * SS + j * 128 + sgrp * 8,
                     Vs + i * 4096 + wave * 512);
        }
        __syncthreads();

        // ---- S = Q K^T ----
        f32x4 sacc[8] = {};
        bf16x8 aq[4];
        #pragma unroll
        for (int kc = 0; kc < 4; kc++)
            aq[kc] = *(const bf16x8*)(const void*)&Qs[(wave * 16 + l15) * 128 + (((kc * 4 + quad) ^ l15) * 8)];
        #pragma unroll
        for (int n = 0; n < 8; n++)
            #pragma unroll
            for (int kc = 0; kc < 4; kc++) {
                bf16x8 bk = *(const bf16x8*)(const void*)&Ks[(n * 16 + l15) * 128 + (((kc * 4 + quad) ^ l15) * 8)];
                sacc[n] = __builtin_amdgcn_mfma_f32_16x16x32_bf16(aq[kc], bk, sacc[n], 0, 0, 0);
            }

        // ---- scale + causal mask + online softmax ----
        float mx[4] = {-1e30f, -1e30f, -1e30f, -1e30f};
        #pragma unroll
        for (int n = 0; n < 8; n++)
            #pragma unroll
            for (int r = 0; r < 4; r++) {
                float v = sacc[n][r] * scale;
                if (j == jlast) {
                    int kl = n * 16 + l15;
                    int ql = wave * 16 + quad * 4 + r;
                    if (kl > ql) v = -1e30f;
                }
                sacc[n][r] = v;
                mx[r] = fmaxf(mx[r], v);
            }
        #pragma unroll
        for (int r = 0; r < 4; r++) {
            mx[r] = fmaxf(mx[r], __shfl_xor(mx[r], 1));
            mx[r] = fmaxf(mx[r], __shfl_xor(mx[r], 2));
            mx[r] = fmaxf(mx[r], __shfl_xor(mx[r], 4));
            mx[r] = fmaxf(mx[r], __shfl_xor(mx[r], 8));
        }
        float alpha[4], rsum[4];
        #pragma unroll
        for (int r = 0; r < 4; r++) {
            float mn = fmaxf(mrun[r], mx[r]);
            alpha[r] = __expf(mrun[r] - mn);
            mrun[r] = mn;
            rsum[r] = 0.f;
        }
        #pragma unroll
        for (int n = 0; n < 8; n++)
            #pragma unroll
            for (int r = 0; r < 4; r++) {
                float p = __expf(sacc[n][r] - mrun[r]);
                sacc[n][r] = p;
                rsum[r] += p;
            }
        #pragma unroll
        for (int r = 0; r < 4; r++) {
            rsum[r] += __shfl_xor(rsum[r], 1);
            rsum[r] += __shfl_xor(rsum[r], 2);
            rsum[r] += __shfl_xor(rsum[r], 4);
            rsum[r] += __shfl_xor(rsum[r], 8);
            lrun[r] = lrun[r] * alpha[r] + rsum[r];
        }
        #pragma unroll
        for (int n = 0; n < 8; n++)
            #pragma unroll
            for (int r = 0; r < 4; r++)
                oacc[n][r] *= alpha[r];

        // ---- P (C-layout) -> wave-private LDS (swizzled) -> A-layout ----
        #pragma unroll
        for (int n = 0; n < 8; n++)
            #pragma unroll
            for (int r = 0; r < 4; r++) {
                int rowp = quad * 4 + r;
                int g = 2 * n + (l15 >> 3);
                Ps[wave * 2048 + rowp * 128 + ((g ^ rowp) * 8) + (l15 & 7)] =
                    __float2bfloat16(sacc[n][r]);
            }
        // P is wave-private: wave-local LDS drain instead of a full barrier
        asm volatile("s_waitcnt lgkmcnt(0)" ::: "memory");

        // ---- O += P @ V ----
        bf16x8 ap[4];
        #pragma unroll
        for (int kc = 0; kc < 4; kc++)
            ap[kc] = *(const bf16x8*)(const void*)&Ps[wave * 2048 + l15 * 128 + (((kc * 4 + quad) ^ l15) * 8)];
        #pragma unroll
        for (int n = 0; n < 8; n++)
            #pragma unroll
            for (int kc = 0; kc < 4; kc++) {
                bf16x8 bv = *(const bf16x8*)(const void*)&Vs[(n * 16 + l15) * 128 + (((kc * 4 + quad) ^ l15) * 8)];
                oacc[n] = __builtin_amdgcn_mfma_f32_16x16x32_bf16(ap[kc], bv, oacc[n], 0, 0, 0);
            }
    }

    #pragma unroll
    for (int n = 0; n < 8; n++)
        #pragma unroll
        for (int r = 0; r < 4; r++) {
            float v = oacc[n][r] / lrun[r];
            out[(size_t)(b * SS + q0 + wave * 16 + quad * 4 + r) * DD + h * DHH + n * 16 + l15] =
                __float2bfloat16(v);
        }
}

// ---------------------------------------------------------------------------
extern "C" void kernel_launch(void* const* d_in, const int* in_sizes, int n_in,
                              void* d_out, int out_size, void* d_ws, size_t ws_size,
                              hipStream_t stream) {
    (void)in_sizes; (void)n_in; (void)out_size; (void)ws_size;
    const float* x     = (const float*)d_in[0];
    const float* ln1_g = (const float*)d_in[2];
    const float* ln1_b = (const float*)d_in[3];
    const float* wq    = (const float*)d_in[4];
    const float* bq    = (const float*)d_in[5];
    const float* wk    = (const float*)d_in[6];
    const float* bk    = (const float*)d_in[7];
    const float* wv    = (const float*)d_in[8];
    const float* bv    = (const float*)d_in[9];
    const float* wo    = (const float*)d_in[10];
    const float* bo    = (const float*)d_in[11];
    const float* ln2_g = (const float*)d_in[12];
    const float* ln2_b = (const float*)d_in[13];
    const float* w_in  = (const float*)d_in[14];
    const float* b_in  = (const float*)d_in[15];
    const float* w_out = (const float*)d_in[16];
    const float* b_out = (const float*)d_in[17];
    float* out = (float*)d_out;

    char* ws = (char*)d_ws;
    const size_t MB = 1024 * 1024;
    bf16*  wt   = (bf16*)(ws + 0 * MB);     // 32 MB (reused per weight)
    bf16*  xn   = (bf16*)(ws + 32 * MB);    // 16 MB (later: attn out)
    bf16*  qb   = (bf16*)(ws + 48 * MB);    // 16 MB (later: xn2)
    float* x1   = (float*)(ws + 64 * MB);   // 32 MB
    bf16*  kbuf = (bf16*)(ws + 96 * MB);    // 16 MB
    bf16*  vbuf = (bf16*)(ws + 112 * MB);   // 16 MB
    bf16*  vtb  = (bf16*)(ws + 128 * MB);   // 16 MB
    bf16*  hb   = (bf16*)(ws + 96 * MB);    // 64 MB (96..160, overlaps k/v/vt after attn)
    bf16*  att  = xn;
    bf16*  xn2  = qb;

    dim3 t256(256), t32x8(32, 8);

    // LN1
    ln_kernel<<<MM, t256, 0, stream>>>(x, ln1_g, ln1_b, xn);

    // Q = xn @ wq + bq
    transpose_cast<<<dim3(DD / 32, DD / 32), t32x8, 0, stream>>>(wq, wt, DD, DD);
    gemm_bt<<<dim3(DD / 128, MM / 128), t256, 0, stream>>>(xn, wt, bq, nullptr, qb, MM, DD, DD, 0);
    // K
    transpose_cast<<<dim3(DD / 32, DD / 32), t32x8, 0, stream>>>(wk, wt, DD, DD);
    gemm_bt<<<dim3(DD / 128, MM / 128), t256, 0, stream>>>(xn, wt, bk, nullptr, kbuf, MM, DD, DD, 0);
    // V
    transpose_cast<<<dim3(DD / 32, DD / 32), t32x8, 0, stream>>>(wv, wt, DD, DD);
    gemm_bt<<<dim3(DD / 128, MM / 128), t256, 0, stream>>>(xn, wt, bv, nullptr, vbuf, MM, DD, DD, 0);
    // V transpose per head
    transpose_v<<<dim3(SS / 32, DHH / 32, BB * HH), t32x8, 0, stream>>>(vbuf, vtb);

    // attention -> att ([token][D] bf16)
    flash_attn<<<dim3(SS / 128, HH, BB), dim3(512), 0, stream>>>(qb, kbuf, vtb, att);

    // x1 = x + att @ wo + bo
    transpose_cast<<<dim3(DD / 32, DD / 32), t32x8, 0, stream>>>(wo, wt, DD, DD);
    gemm_bt<<<dim3(DD / 128, MM / 128), t256, 0, stream>>>(att, wt, bo, x, x1, MM, DD, DD, 1);

    // LN2
    ln_kernel<<<MM, t256, 0, stream>>>(x1, ln2_g, ln2_b, xn2);

    // h = gelu(xn2 @ w_in + b_in)
    transpose_cast<<<dim3(DFF / 32, DD / 32), t32x8, 0, stream>>>(w_in, wt, DD, DFF);
    gemm_bt<<<dim3(DFF / 128, MM / 128), t256, 0, stream>>>(xn2, wt, b_in, nullptr, hb, MM, DFF, DD, 2);

    // out = x1 + h @ w_out + b_out
    transpose_cast<<<dim3(DD / 32, DFF / 32), t32x8, 0, stream>>>(w_out, wt, DFF, DD);
    gemm_bt<<<dim3(DD / 128, MM / 128), t256, 0, stream>>>(hb, wt, b_out, x1, out, MM, DD, DFF, 1);
}

// Round 3
// 1074.794 us; speedup vs baseline: 1.2580x; 1.0134x over previous
//
#include <hip/hip_runtime.h>
#include <hip/hip_bf16.h>

#define BB   2
#define SS   2048
#define DD   2048
#define HH   16
#define DHH  128
#define DFF  8192
#define MM   (BB*SS)   // 4096 tokens
#define QKD  6144      // fused qkv row width

typedef __hip_bfloat16 bf16;
typedef __bf16 bf16x8 __attribute__((ext_vector_type(8)));
typedef float  f32x4 __attribute__((ext_vector_type(4)));

// -------- async global->LDS, 16B per lane; lds base must be wave-uniform --------
__device__ __forceinline__ void gl2lds16(const void* g, void* lds_uniform_base) {
    __builtin_amdgcn_global_load_lds(
        (const __attribute__((address_space(1))) void*)g,
        (__attribute__((address_space(3))) void*)lds_uniform_base,
        16, 0, 0);
}

// ---------------------------------------------------------------------------
// LayerNorm: one block per row (D=2048), 256 threads, fp32 in -> bf16 out
// ---------------------------------------------------------------------------
__global__ __launch_bounds__(256) void ln_kernel(const float* __restrict__ x,
                                                 const float* __restrict__ g,
                                                 const float* __restrict__ b,
                                                 bf16* __restrict__ out) {
    int row = blockIdx.x, tid = threadIdx.x;
    const float4* xr = (const float4*)(x + (size_t)row * DD);
    float4 v0 = xr[tid];
    float4 v1 = xr[tid + 256];
    float s  = v0.x + v0.y + v0.z + v0.w + v1.x + v1.y + v1.z + v1.w;
    float s2 = v0.x*v0.x + v0.y*v0.y + v0.z*v0.z + v0.w*v0.w
             + v1.x*v1.x + v1.y*v1.y + v1.z*v1.z + v1.w*v1.w;
    #pragma unroll
    for (int m = 32; m >= 1; m >>= 1) { s += __shfl_xor(s, m); s2 += __shfl_xor(s2, m); }
    __shared__ float red[8];
    int wv = tid >> 6;
    if ((tid & 63) == 0) { red[wv] = s; red[wv + 4] = s2; }
    __syncthreads();
    s  = red[0] + red[1] + red[2] + red[3];
    s2 = red[4] + red[5] + red[6] + red[7];
    float mean = s * (1.0f / DD);
    float rs = rsqrtf(s2 * (1.0f / DD) - mean * mean + 1e-5f);
    bf16* o = out + (size_t)row * DD;
    int c0 = tid * 4, c1 = (tid + 256) * 4;
    float a0[4] = {v0.x, v0.y, v0.z, v0.w};
    float a1[4] = {v1.x, v1.y, v1.z, v1.w};
    #pragma unroll
    for (int j = 0; j < 4; j++) {
        o[c0 + j] = __float2bfloat16((a0[j] - mean) * rs * g[c0 + j] + b[c0 + j]);
        o[c1 + j] = __float2bfloat16((a1[j] - mean) * rs * g[c1 + j] + b[c1 + j]);
    }
}

// ---------------------------------------------------------------------------
// Transpose + fp32->bf16 cast: W[K][N] -> Wt[N][K]
// ---------------------------------------------------------------------------
__global__ __launch_bounds__(256) void transpose_cast(const float* __restrict__ W,
                                                      bf16* __restrict__ Wt,
                                                      int K, int N) {
    __shared__ float t[32][33];
    int n0 = blockIdx.x * 32, k0 = blockIdx.y * 32;
    int tx = threadIdx.x, ty = threadIdx.y;
    #pragma unroll
    for (int i = 0; i < 4; i++)
        t[ty + i * 8][tx] = W[(size_t)(k0 + ty + i * 8) * N + n0 + tx];
    __syncthreads();
    #pragma unroll
    for (int i = 0; i < 4; i++)
        Wt[(size_t)(n0 + ty + i * 8) * K + k0 + tx] = __float2bfloat16(t[tx][ty + i * 8]);
}

// ---------------------------------------------------------------------------
// concat 3 bias vectors (2048 each) into one 6144 buffer
// ---------------------------------------------------------------------------
__global__ __launch_bounds__(256) void concat3(const float* __restrict__ a,
                                               const float* __restrict__ b,
                                               const float* __restrict__ c,
                                               float* __restrict__ o) {
    int i = blockIdx.x * 256 + threadIdx.x;
    o[i] = i < 2048 ? a[i] : (i < 4096 ? b[i - 2048] : c[i - 4096]);
}

// ---------------------------------------------------------------------------
// V transpose per head from fused qkv: qkv[b*S+s][4096 + h*DH+dh] (bf16, row
// stride QKD) -> vt[(b*H+h)*DH+dh][s]
// ---------------------------------------------------------------------------
__global__ __launch_bounds__(256) void transpose_v(const bf16* __restrict__ qkv,
                                                   bf16* __restrict__ vt) {
    __shared__ bf16 t[32][33];
    int s0 = blockIdx.x * 32, d0 = blockIdx.y * 32;
    int bh = blockIdx.z;
    int b = bh >> 4, h = bh & 15;
    int tx = threadIdx.x, ty = threadIdx.y;
    #pragma unroll
    for (int i = 0; i < 4; i++)
        t[ty + i * 8][tx] = qkv[(size_t)(b * SS + s0 + ty + i * 8) * QKD + 4096 + h * DHH + d0 + tx];
    __syncthreads();
    #pragma unroll
    for (int i = 0; i < 4; i++)
        vt[(size_t)((b * HH + h) * DHH + d0 + ty + i * 8) * SS + s0 + tx] = t[tx][ty + i * 8];
}

// ---------------------------------------------------------------------------
// GEMM: C[M][N] = A[M][K] @ Bt[N][K]^T + bias  (+ epilogue)
// epi 0: store bf16; epi 1: store fp32 (+resid, direct); epi 2: gelu -> bf16
// bf16 epilogues (0,2) repack through padded LDS -> 32 B/lane full-line
// stores (no write-allocate RMW). epi1 is already 64B/quad coalesced.
// BM=BN=128, BK=32, 256 threads (4 waves, 2x2), 4x4 MFMA 16x16x32 per wave
// ---------------------------------------------------------------------------
__global__ __launch_bounds__(256) void gemm_bt(const bf16* __restrict__ A,
                                               const bf16* __restrict__ Bt,
                                               const float* __restrict__ bias,
                                               const float* __restrict__ resid,
                                               void* __restrict__ Cout,
                                               int M, int N, int K, int epi) {
    __shared__ __align__(16) bf16 As[128 * 32];
    __shared__ __align__(16) bf16 Bs[128 * 32];
    __shared__ __align__(16) float Es[4 * 16 * 68];   // epilogue repack, wave-private slices
    int tid = threadIdx.x;
    int lane = tid & 63, wave = tid >> 6;
    int quad = lane >> 4, l15 = lane & 15;
    int wm = wave >> 1, wn = wave & 1;
    int bm0 = blockIdx.y * 128, bn0 = blockIdx.x * 128;
    const bf16* Ag = A + (size_t)bm0 * K;
    const bf16* Bg = Bt + (size_t)bn0 * K;
    f32x4 acc[4][4] = {};

    for (int kt = 0; kt < K; kt += 32) {
        __syncthreads();
        #pragma unroll
        for (int i = 0; i < 2; i++) {
            int chunk = i * 256 + tid;
            int row = chunk >> 2, c8 = chunk & 3;
            gl2lds16(Ag + (size_t)row * K + kt + c8 * 8, As + (i * 256 + wave * 64) * 8);
        }
        #pragma unroll
        for (int i = 0; i < 2; i++) {
            int chunk = i * 256 + tid;
            int row = chunk >> 2, c8 = chunk & 3;
            gl2lds16(Bg + (size_t)row * K + kt + c8 * 8, Bs + (i * 256 + wave * 64) * 8);
        }
        __syncthreads();
        bf16x8 af[4], bfr[4];
        #pragma unroll
        for (int mt = 0; mt < 4; mt++)
            af[mt] = *(const bf16x8*)(const void*)&As[(wm * 64 + mt * 16 + l15) * 32 + quad * 8];
        #pragma unroll
        for (int nt = 0; nt < 4; nt++)
            bfr[nt] = *(const bf16x8*)(const void*)&Bs[(wn * 64 + nt * 16 + l15) * 32 + quad * 8];
        #pragma unroll
        for (int mt = 0; mt < 4; mt++)
            #pragma unroll
            for (int nt = 0; nt < 4; nt++)
                acc[mt][nt] = __builtin_amdgcn_mfma_f32_16x16x32_bf16(af[mt], bfr[nt], acc[mt][nt], 0, 0, 0);
    }

    if (epi == 1) {
        // fp32 + residual, direct C-layout stores (64 B contiguous per quad)
        #pragma unroll
        for (int nt = 0; nt < 4; nt++) {
            int col = bn0 + wn * 64 + nt * 16 + l15;
            float bv = bias[col];
            #pragma unroll
            for (int mt = 0; mt < 4; mt++)
                #pragma unroll
                for (int r = 0; r < 4; r++) {
                    int row = bm0 + wm * 64 + mt * 16 + quad * 4 + r;
                    size_t idx = (size_t)row * N + col;
                    ((float*)Cout)[idx] = acc[mt][nt][r] + bv + resid[idx];
                }
        }
    } else {
        // bf16 out: LDS repack -> full-line stores
        float bv[4];
        #pragma unroll
        for (int nt = 0; nt < 4; nt++) bv[nt] = bias[bn0 + wn * 64 + nt * 16 + l15];
        int rr = lane >> 2, cc = lane & 3;
        #pragma unroll
        for (int mt = 0; mt < 4; mt++) {
            #pragma unroll
            for (int nt = 0; nt < 4; nt++)
                #pragma unroll
                for (int r = 0; r < 4; r++)
                    Es[wave * 1088 + (quad * 4 + r) * 68 + nt * 16 + l15] = acc[mt][nt][r] + bv[nt];
            asm volatile("s_waitcnt lgkmcnt(0)" ::: "memory");
            float vals[16];
            #pragma unroll
            for (int j4 = 0; j4 < 4; j4++) {
                float4 f = *(const float4*)&Es[wave * 1088 + rr * 68 + cc * 16 + j4 * 4];
                vals[j4 * 4 + 0] = f.x; vals[j4 * 4 + 1] = f.y;
                vals[j4 * 4 + 2] = f.z; vals[j4 * 4 + 3] = f.w;
            }
            asm volatile("s_waitcnt lgkmcnt(0)" ::: "memory");
            union { bf16 h[16]; uint4 u[2]; } ob;
            #pragma unroll
            for (int j = 0; j < 16; j++) {
                float v = vals[j];
                if (epi == 2) v = 0.5f * v * (1.0f + erff(v * 0.70710678118654752f));
                ob.h[j] = __float2bfloat16(v);
            }
            int grow = bm0 + wm * 64 + mt * 16 + rr;
            int gcol = bn0 + wn * 64 + cc * 16;
            uint4* dst = (uint4*)((bf16*)Cout + (size_t)grow * N + gcol);
            dst[0] = ob.u[0];
            dst[1] = ob.u[1];
        }
    }
}

// ---------------------------------------------------------------------------
// Flash attention: grid (S/128, H, B), 512 threads (8 waves).
// BM=128 Q rows (16 per wave), K-tiles of 128 keys, online softmax.
// All LDS tiles XOR-swizzled at 16B-group granularity (see r2 notes).
// q,k from fused qkv [token][QKD]; vt: [(b*H+h)*DH+dh][s]; out: [token][D] bf16
// ---------------------------------------------------------------------------
__global__ __launch_bounds__(512) void flash_attn(const bf16* __restrict__ qkv,
                                                  const bf16* __restrict__ vt,
                                                  bf16* __restrict__ out) {
    __shared__ __align__(16) bf16 Qs[128 * 128];
    __shared__ __align__(16) bf16 Ks[128 * 128];
    __shared__ __align__(16) bf16 Vs[128 * 128];   // [dh][key]
    __shared__ __align__(16) bf16 Ps[8 * 16 * 128];
    int tid = threadIdx.x;
    int lane = tid & 63, wave = tid >> 6;
    int quad = lane >> 4, l15 = lane & 15;
    // causal load-balance: pair tile k with tile 15-k in adjacent dispatch ids
    int xr = blockIdx.x;
    int t = (xr & 1) ? (15 - (xr >> 1)) : (xr >> 1);
    int q0 = t * 128;
    int h = blockIdx.y, b = blockIdx.z;
    int jlast = t;
    const float scale = 0.088388347648318447f;  // 1/sqrt(128)

    int srow = tid >> 4;                    // 0..31 (row within 32-row chunk)
    int sgrp = (tid & 15) ^ (srow & 15);    // swizzled source 16B-group

    const bf16* qb = qkv + h * DHH;         // q cols [0,2048)
    const bf16* kb = qkv + 2048 + h * DHH;  // k cols [2048,4096)

    // ---- stage Q (swizzled) ----
    #pragma unroll
    for (int i = 0; i < 4; i++) {
        int row = i * 32 + srow;
        gl2lds16(qb + (size_t)(b * SS + q0 + row) * QKD + sgrp * 8,
                 Qs + i * 4096 + wave * 512);
    }

    f32x4 oacc[8] = {};
    float mrun[4] = {-1e30f, -1e30f, -1e30f, -1e30f};
    float lrun[4] = {0.f, 0.f, 0.f, 0.f};

    for (int j = 0; j <= jlast; j++) {
        __syncthreads();
        #pragma unroll
        for (int i = 0; i < 4; i++) {
            int row = i * 32 + srow;
            gl2lds16(kb + (size_t)(b * SS + j * 128 + row) * QKD + sgrp * 8,
                     Ks + i * 4096 + wave * 512);
        }
        #pragma unroll
        for (int i = 0; i < 4; i++) {
            int row = i * 32 + srow;
            gl2lds16(vt + (size_t)((b * HH + h) * DHH + row) * SS + j * 128 + sgrp * 8,
                     Vs + i * 4096 + wave * 512);
        }
        __syncthreads();

        // ---- S = Q K^T ----
        f32x4 sacc[8] = {};
        bf16x8 aq[4];
        #pragma unroll
        for (int kc = 0; kc < 4; kc++)
            aq[kc] = *(const bf16x8*)(const void*)&Qs[(wave * 16 + l15) * 128 + (((kc * 4 + quad) ^ l15) * 8)];
        #pragma unroll
        for (int n = 0; n < 8; n++)
            #pragma unroll
            for (int kc = 0; kc < 4; kc++) {
                bf16x8 bk = *(const bf16x8*)(const void*)&Ks[(n * 16 + l15) * 128 + (((kc * 4 + quad) ^ l15) * 8)];
                sacc[n] = __builtin_amdgcn_mfma_f32_16x16x32_bf16(aq[kc], bk, sacc[n], 0, 0, 0);
            }

        // ---- scale + causal mask + online softmax ----
        float mx[4] = {-1e30f, -1e30f, -1e30f, -1e30f};
        #pragma unroll
        for (int n = 0; n < 8; n++)
            #pragma unroll
            for (int r = 0; r < 4; r++) {
                float v = sacc[n][r] * scale;
                if (j == jlast) {
                    int kl = n * 16 + l15;
                    int ql = wave * 16 + quad * 4 + r;
                    if (kl > ql) v = -1e30f;
                }
                sacc[n][r] = v;
                mx[r] = fmaxf(mx[r], v);
            }
        #pragma unroll
        for (int r = 0; r < 4; r++) {
            mx[r] = fmaxf(mx[r], __shfl_xor(mx[r], 1));
            mx[r] = fmaxf(mx[r], __shfl_xor(mx[r], 2));
            mx[r] = fmaxf(mx[r], __shfl_xor(mx[r], 4));
            mx[r] = fmaxf(mx[r], __shfl_xor(mx[r], 8));
        }
        float alpha[4], rsum[4];
        #pragma unroll
        for (int r = 0; r < 4; r++) {
            float mn = fmaxf(mrun[r], mx[r]);
            alpha[r] = __expf(mrun[r] - mn);
            mrun[r] = mn;
            rsum[r] = 0.f;
        }
        #pragma unroll
        for (int n = 0; n < 8; n++)
            #pragma unroll
            for (int r = 0; r < 4; r++) {
                float p = __expf(sacc[n][r] - mrun[r]);
                sacc[n][r] = p;
                rsum[r] += p;
            }
        #pragma unroll
        for (int r = 0; r < 4; r++) {
            rsum[r] += __shfl_xor(rsum[r], 1);
            rsum[r] += __shfl_xor(rsum[r], 2);
            rsum[r] += __shfl_xor(rsum[r], 4);
            rsum[r] += __shfl_xor(rsum[r], 8);
            lrun[r] = lrun[r] * alpha[r] + rsum[r];
        }
        #pragma unroll
        for (int n = 0; n < 8; n++)
            #pragma unroll
            for (int r = 0; r < 4; r++)
                oacc[n][r] *= alpha[r];

        // ---- P (C-layout) -> wave-private LDS (swizzled) -> A-layout ----
        #pragma unroll
        for (int n = 0; n < 8; n++)
            #pragma unroll
            for (int r = 0; r < 4; r++) {
                int rowp = quad * 4 + r;
                int g = 2 * n + (l15 >> 3);
                Ps[wave * 2048 + rowp * 128 + ((g ^ rowp) * 8) + (l15 & 7)] =
                    __float2bfloat16(sacc[n][r]);
            }
        // P is wave-private: wave-local LDS drain instead of a full barrier
        asm volatile("s_waitcnt lgkmcnt(0)" ::: "memory");

        // ---- O += P @ V ----
        bf16x8 ap[4];
        #pragma unroll
        for (int kc = 0; kc < 4; kc++)
            ap[kc] = *(const bf16x8*)(const void*)&Ps[wave * 2048 + l15 * 128 + (((kc * 4 + quad) ^ l15) * 8)];
        #pragma unroll
        for (int n = 0; n < 8; n++)
            #pragma unroll
            for (int kc = 0; kc < 4; kc++) {
                bf16x8 bv = *(const bf16x8*)(const void*)&Vs[(n * 16 + l15) * 128 + (((kc * 4 + quad) ^ l15) * 8)];
                oacc[n] = __builtin_amdgcn_mfma_f32_16x16x32_bf16(ap[kc], bv, oacc[n], 0, 0, 0);
            }
    }

    #pragma unroll
    for (int n = 0; n < 8; n++)
        #pragma unroll
        for (int r = 0; r < 4; r++) {
            float v = oacc[n][r] / lrun[r];
            out[(size_t)(b * SS + q0 + wave * 16 + quad * 4 + r) * DD + h * DHH + n * 16 + l15] =
                __float2bfloat16(v);
        }
}

// ---------------------------------------------------------------------------
extern "C" void kernel_launch(void* const* d_in, const int* in_sizes, int n_in,
                              void* d_out, int out_size, void* d_ws, size_t ws_size,
                              hipStream_t stream) {
    (void)in_sizes; (void)n_in; (void)out_size; (void)ws_size;
    const float* x     = (const float*)d_in[0];
    const float* ln1_g = (const float*)d_in[2];
    const float* ln1_b = (const float*)d_in[3];
    const float* wq    = (const float*)d_in[4];
    const float* bq    = (const float*)d_in[5];
    const float* wk    = (const float*)d_in[6];
    const float* bk    = (const float*)d_in[7];
    const float* wv    = (const float*)d_in[8];
    const float* bv    = (const float*)d_in[9];
    const float* wo    = (const float*)d_in[10];
    const float* bo    = (const float*)d_in[11];
    const float* ln2_g = (const float*)d_in[12];
    const float* ln2_b = (const float*)d_in[13];
    const float* w_in  = (const float*)d_in[14];
    const float* b_in  = (const float*)d_in[15];
    const float* w_out = (const float*)d_in[16];
    const float* b_out = (const float*)d_in[17];
    float* out = (float*)d_out;

    char* ws = (char*)d_ws;
    const size_t MB = 1024 * 1024;
    bf16*  wt   = (bf16*)(ws + 0 * MB);     // 32 MB (qkv^T fused 24 MB, or per-weight up to 32 MB)
    bf16*  xn   = (bf16*)(ws + 32 * MB);    // 16 MB (LN1 out; later att; later xn2)
    bf16*  qkvb = (bf16*)(ws + 48 * MB);    // 48 MB fused qkv [token][6144]
    bf16*  vtb  = (bf16*)(ws + 96 * MB);    // 16 MB
    float* x1   = (float*)(ws + 112 * MB);  // 32 MB
    float* bcat = (float*)(ws + 144 * MB);  // 24 KB
    bf16*  hb   = (bf16*)(ws + 48 * MB);    // 64 MB (reuses qkvb+vtb after attention)
    bf16*  att  = xn;
    bf16*  xn2  = xn;

    dim3 t256(256), t32x8(32, 8);

    // LN1
    ln_kernel<<<MM, t256, 0, stream>>>(x, ln1_g, ln1_b, xn);

    // fused QKV: wt = [wq^T ; wk^T ; wv^T] (6144 x 2048)
    transpose_cast<<<dim3(DD / 32, DD / 32), t32x8, 0, stream>>>(wq, wt, DD, DD);
    transpose_cast<<<dim3(DD / 32, DD / 32), t32x8, 0, stream>>>(wk, wt + 2048 * 2048, DD, DD);
    transpose_cast<<<dim3(DD / 32, DD / 32), t32x8, 0, stream>>>(wv, wt + 2 * 2048 * 2048, DD, DD);
    concat3<<<QKD / 256, t256, 0, stream>>>(bq, bk, bv, bcat);
    gemm_bt<<<dim3(QKD / 128, MM / 128), t256, 0, stream>>>(xn, wt, bcat, nullptr, qkvb, MM, QKD, DD, 0);

    // V transpose per head
    transpose_v<<<dim3(SS / 32, DHH / 32, BB * HH), t32x8, 0, stream>>>(qkvb, vtb);

    // attention -> att ([token][D] bf16)
    flash_attn<<<dim3(SS / 128, HH, BB), dim3(512), 0, stream>>>(qkvb, vtb, att);

    // x1 = x + att @ wo + bo
    transpose_cast<<<dim3(DD / 32, DD / 32), t32x8, 0, stream>>>(wo, wt, DD, DD);
    gemm_bt<<<dim3(DD / 128, MM / 128), t256, 0, stream>>>(att, wt, bo, x, x1, MM, DD, DD, 1);

    // LN2 (xn2 reuses xn region; att dead after O-proj)
    ln_kernel<<<MM, t256, 0, stream>>>(x1, ln2_g, ln2_b, xn2);

    // h = gelu(xn2 @ w_in + b_in)
    transpose_cast<<<dim3(DFF / 32, DD / 32), t32x8, 0, stream>>>(w_in, wt, DD, DFF);
    gemm_bt<<<dim3(DFF / 128, MM / 128), t256, 0, stream>>>(xn2, wt, b_in, nullptr, hb, MM, DFF, DD, 2);

    // out = x1 + h @ w_out + b_out
    transpose_cast<<<dim3(DD / 32, DFF / 32), t32x8, 0, stream>>>(w_out, wt, DFF, DD);
    gemm_bt<<<dim3(DD / 128, MM / 128), t256, 0, stream>>>(hb, wt, b_out, x1, out, MM, DD, DFF, 1);
}